// Round 3
// baseline (570.916 us; speedup 1.0000x reference)
//
#include <hip/hip_runtime.h>

#define DM   1024
#define LSEQ 512
#define NBK  192   // B*3
#define NCH  8     // L-chunks of 64 rows
#define HDIM 1024
#define BDIM 64

// ---------------------------------------------------------------------------
// Kernel 0: detect mask storage format. Scan first NBK*LSEQ bytes as uint32.
// int32 layout (values 0/1): every word's bytes 1..3 are zero.
// bool  layout: masked tail bytes (=1) land at offsets %4 != 0 almost surely.
// flag = 1 -> int32 layout, 0 -> 1-byte bool layout.
// ---------------------------------------------------------------------------
__global__ __launch_bounds__(256) void detect_kernel(
    const unsigned* __restrict__ m, int* __restrict__ flag)
{
    __shared__ int s[256];
    const int t = threadIdx.x;
    unsigned any = 0;
    for (int i = t; i < (NBK * LSEQ / 4); i += 256)
        any |= m[i] & 0xFFFFFF00u;
    s[t] = (any != 0);
    __syncthreads();
    for (int sf = 128; sf > 0; sf >>= 1) {
        if (t < sf) s[t] |= s[t + sf];
        __syncthreads();
    }
    if (t == 0) *flag = (s[0] == 0) ? 1 : 0;
}

// ---------------------------------------------------------------------------
// Kernel 1: zero y, per-(b,k) valid counts (branch on mask format), softmax
// combination weights. grid = 256 blocks x 256 threads.
// ---------------------------------------------------------------------------
__global__ __launch_bounds__(256) void prep_kernel(
    const float* __restrict__ gf, const unsigned char* __restrict__ mask,
    const float* __restrict__ Wc, const float* __restrict__ bc,
    const int* __restrict__ flagp,
    float* __restrict__ w, int* __restrict__ cnts, float* __restrict__ y)
{
    const int bid = blockIdx.x, t = threadIdx.x;
    y[bid * 256 + t] = 0.0f;

    if (bid < NBK) {
        __shared__ int sc[256];
        int c = 0;
        if (*flagp) {  // int32 mask: row of 512 ints
            const unsigned* row = (const unsigned*)mask + bid * LSEQ;
            c = (int)(row[t] == 0) + (int)(row[t + 256] == 0);
        } else {       // bool mask: row of 512 bytes = 128 words
            if (t < 128) {
                unsigned u = ((const unsigned*)mask)[bid * 128 + t];
                c = (int)((u & 0xFFu) == 0) + (int)((u & 0xFF00u) == 0)
                  + (int)((u & 0xFF0000u) == 0) + (int)((u & 0xFF000000u) == 0);
            }
        }
        sc[t] = c;
        __syncthreads();
        for (int s = 128; s > 0; s >>= 1) {
            if (t < s) sc[t] += sc[t + s];
            __syncthreads();
        }
        if (t == 0) cnts[bid] = sc[0];
    } else if (bid == NBK) {
        __shared__ float sz0[256], sz1[256], sz2[256];
        float p0 = 0.f, p1 = 0.f, p2 = 0.f;
        #pragma unroll
        for (int j = 0; j < 4; ++j) {
            float g = gf[t * 4 + j];
            p0 += Wc[0 * DM + t * 4 + j] * g;
            p1 += Wc[1 * DM + t * 4 + j] * g;
            p2 += Wc[2 * DM + t * 4 + j] * g;
        }
        sz0[t] = p0; sz1[t] = p1; sz2[t] = p2;
        __syncthreads();
        for (int s = 128; s > 0; s >>= 1) {
            if (t < s) { sz0[t] += sz0[t+s]; sz1[t] += sz1[t+s]; sz2[t] += sz2[t+s]; }
            __syncthreads();
        }
        if (t == 0) {
            float z0 = sz0[0] + bc[0], z1 = sz1[0] + bc[1], z2 = sz2[0] + bc[2];
            float m  = fmaxf(z0, fmaxf(z1, z2));
            float e0 = expf(z0 - m), e1 = expf(z1 - m), e2 = expf(z2 - m);
            float inv = 1.0f / (e0 + e1 + e2);
            w[0] = e0 * inv; w[1] = e1 * inv; w[2] = e2 * inv;
        }
    }
}

// ---------------------------------------------------------------------------
// Kernel 2: y[b,d] += (w_k/len) * sum over valid rows of x[b,k,l,d].
// grid = NBK*NCH blocks x 256 threads; block owns (bk, 64-row chunk).
// Mask is monotone => valid rows are exactly l < len; skip the rest (halves
// HBM traffic vs. reading everything).
// ---------------------------------------------------------------------------
__global__ __launch_bounds__(256) void pool_kernel(
    const float4* __restrict__ x4, const float* __restrict__ w,
    const int* __restrict__ cnts, float* __restrict__ y)
{
    const int bid = blockIdx.x;
    const int bk  = bid >> 3;
    const int ch  = bid & 7;
    const int len = cnts[bk];
    const int l0  = ch << 6;
    if (l0 >= len) return;
    const int nrows = min(64, len - l0);

    const int t = threadIdx.x;
    const int b = bk / 3;
    const int k = bk - b * 3;
    const float scale = w[k] / (float)len;

    const float4* xp = x4 + ((bk * LSEQ + l0) * (DM / 4)) + t;

    float ax0=0.f, ay0=0.f, az0=0.f, aw0=0.f;
    float ax1=0.f, ay1=0.f, az1=0.f, aw1=0.f;
    int r = 0;
    for (; r + 2 <= nrows; r += 2) {
        float4 v0 = xp[(r    ) * (DM / 4)];
        float4 v1 = xp[(r + 1) * (DM / 4)];
        ax0 += v0.x; ay0 += v0.y; az0 += v0.z; aw0 += v0.w;
        ax1 += v1.x; ay1 += v1.y; az1 += v1.z; aw1 += v1.w;
    }
    if (r < nrows) {
        float4 v0 = xp[r * (DM / 4)];
        ax0 += v0.x; ay0 += v0.y; az0 += v0.z; aw0 += v0.w;
    }
    ax0 = (ax0 + ax1) * scale;
    ay0 = (ay0 + ay1) * scale;
    az0 = (az0 + az1) * scale;
    aw0 = (aw0 + aw1) * scale;

    float* yp = y + b * DM + t * 4;
    atomicAdd(yp + 0, ax0);
    atomicAdd(yp + 1, ay0);
    atomicAdd(yp + 2, az0);
    atomicAdd(yp + 3, aw0);
}

// ---------------------------------------------------------------------------
// Kernel 3: feature[b,h] = dot(y[b,:], W_proj[h,:]) + b_proj[h].
// Thread (b = t&63, hh = t>>6) computes one output; W row is wave-uniform
// (broadcast, read exactly once = 4 MB); y rows are L1/L2-resident.
// ---------------------------------------------------------------------------
__global__ __launch_bounds__(256) void out_kernel(
    const float4* __restrict__ y4, const float4* __restrict__ W4,
    const float* __restrict__ bp, float* __restrict__ out)
{
    const int t = threadIdx.x;
    const int b = t & 63;
    const int h = blockIdx.x * 4 + (t >> 6);

    const float4* yp = y4 + b * (DM / 4);
    const float4* wp = W4 + h * (DM / 4);

    float acc = 0.f;
    #pragma unroll 8
    for (int i = 0; i < DM / 4; ++i) {
        float4 yv = yp[i];
        float4 wv = wp[i];
        acc += yv.x * wv.x;
        acc += yv.y * wv.y;
        acc += yv.z * wv.z;
        acc += yv.w * wv.w;
    }
    out[b * HDIM + h] = acc + bp[h];
}

extern "C" void kernel_launch(void* const* d_in, const int* in_sizes, int n_in,
                              void* d_out, int out_size, void* d_ws, size_t ws_size,
                              hipStream_t stream) {
    const float*         gf   = (const float*)d_in[0];         // (DM,)
    const float*         x    = (const float*)d_in[1];         // (B,3,L,DM)
    const unsigned char* mask = (const unsigned char*)d_in[2]; // (B,3,L)
    const float*         Wp   = (const float*)d_in[3];         // (H,DM)
    const float*         bp   = (const float*)d_in[4];         // (H,)
    const float*         Wc   = (const float*)d_in[5];         // (3,DM)
    const float*         bc   = (const float*)d_in[6];         // (3,)
    float* out = (float*)d_out;                                // (B,H)

    // ws layout (floats): [0..3]=w, [4..195]=cnts(int), [196]=flag,
    //                     [256..65791]=y
    float* wsf  = (float*)d_ws;
    float* w    = wsf;
    int*   cnts = (int*)(wsf + 4);
    int*   flag = (int*)(wsf + 196);
    float* y    = wsf + 256;   // byte offset 1024 -> float4-aligned

    detect_kernel<<<1, 256, 0, stream>>>((const unsigned*)mask, flag);
    prep_kernel<<<256, 256, 0, stream>>>(gf, mask, Wc, bc, flag, w, cnts, y);
    pool_kernel<<<NBK * NCH, 256, 0, stream>>>((const float4*)x, w, cnts, y);
    out_kernel<<<HDIM / 4, 256, 0, stream>>>((const float4*)y, (const float4*)Wp, bp, out);
}

// Round 6
// 568.708 us; speedup vs baseline: 1.0039x; 1.0039x over previous
//
#include <hip/hip_runtime.h>

#define DM   1024
#define LSEQ 512
#define NBK  192   // B*3
#define NCH  8     // L-chunks of 64 rows
#define HDIM 1024

// ---------------------------------------------------------------------------
// Kernel 0: detect mask storage format. Scan first NBK*LSEQ bytes as uint32.
// int32 layout (values 0/1): every word's bytes 1..3 are zero.
// bool  layout: masked tail bytes (=1) land at offsets %4 != 0 almost surely.
// flag = 1 -> int32 layout, 0 -> 1-byte bool layout.  (Verified correct in R3.)
// ---------------------------------------------------------------------------
__global__ __launch_bounds__(256) void detect_kernel(
    const unsigned* __restrict__ m, int* __restrict__ flag)
{
    __shared__ int s[256];
    const int t = threadIdx.x;
    unsigned any = 0;
    for (int i = t; i < (NBK * LSEQ / 4); i += 256)
        any |= m[i] & 0xFFFFFF00u;
    s[t] = (any != 0);
    __syncthreads();
    for (int sf = 128; sf > 0; sf >>= 1) {
        if (t < sf) s[t] |= s[t + sf];
        __syncthreads();
    }
    if (t == 0) *flag = (s[0] == 0) ? 1 : 0;
}

// ---------------------------------------------------------------------------
// Kernel 1: zero y, per-(b,k) valid counts (branch on mask format), softmax
// combination weights. grid = 256 blocks x 256 threads.  (Verified in R3.)
// ---------------------------------------------------------------------------
__global__ __launch_bounds__(256) void prep_kernel(
    const float* __restrict__ gf, const unsigned char* __restrict__ mask,
    const float* __restrict__ Wc, const float* __restrict__ bc,
    const int* __restrict__ flagp,
    float* __restrict__ w, int* __restrict__ cnts, float* __restrict__ y)
{
    const int bid = blockIdx.x, t = threadIdx.x;
    y[bid * 256 + t] = 0.0f;

    if (bid < NBK) {
        __shared__ int sc[256];
        int c = 0;
        if (*flagp) {  // int32 mask: row of 512 ints
            const unsigned* row = (const unsigned*)mask + bid * LSEQ;
            c = (int)(row[t] == 0) + (int)(row[t + 256] == 0);
        } else {       // bool mask: row of 512 bytes = 128 words
            if (t < 128) {
                unsigned u = ((const unsigned*)mask)[bid * 128 + t];
                c = (int)((u & 0xFFu) == 0) + (int)((u & 0xFF00u) == 0)
                  + (int)((u & 0xFF0000u) == 0) + (int)((u & 0xFF000000u) == 0);
            }
        }
        sc[t] = c;
        __syncthreads();
        for (int s = 128; s > 0; s >>= 1) {
            if (t < s) sc[t] += sc[t + s];
            __syncthreads();
        }
        if (t == 0) cnts[bid] = sc[0];
    } else if (bid == NBK) {
        __shared__ float sz0[256], sz1[256], sz2[256];
        float p0 = 0.f, p1 = 0.f, p2 = 0.f;
        #pragma unroll
        for (int j = 0; j < 4; ++j) {
            float g = gf[t * 4 + j];
            p0 += Wc[0 * DM + t * 4 + j] * g;
            p1 += Wc[1 * DM + t * 4 + j] * g;
            p2 += Wc[2 * DM + t * 4 + j] * g;
        }
        sz0[t] = p0; sz1[t] = p1; sz2[t] = p2;
        __syncthreads();
        for (int s = 128; s > 0; s >>= 1) {
            if (t < s) { sz0[t] += sz0[t+s]; sz1[t] += sz1[t+s]; sz2[t] += sz2[t+s]; }
            __syncthreads();
        }
        if (t == 0) {
            float z0 = sz0[0] + bc[0], z1 = sz1[0] + bc[1], z2 = sz2[0] + bc[2];
            float m  = fmaxf(z0, fmaxf(z1, z2));
            float e0 = expf(z0 - m), e1 = expf(z1 - m), e2 = expf(z2 - m);
            float inv = 1.0f / (e0 + e1 + e2);
            w[0] = e0 * inv; w[1] = e1 * inv; w[2] = e2 * inv;
        }
    }
}

// ---------------------------------------------------------------------------
// Kernel 2: y[b,d] += (w_k/len) * sum over valid rows of x[b,k,l,d].
// grid = NBK*NCH blocks x 256 threads; block owns (bk, 64-row chunk).
// Mask monotone => valid rows are exactly l < len; skip the rest (~200 MB
// stream = the roofline term).  (Verified in R3.)
// ---------------------------------------------------------------------------
__global__ __launch_bounds__(256) void pool_kernel(
    const float4* __restrict__ x4, const float* __restrict__ w,
    const int* __restrict__ cnts, float* __restrict__ y)
{
    const int bid = blockIdx.x;
    const int bk  = bid >> 3;
    const int ch  = bid & 7;
    const int len = cnts[bk];
    const int l0  = ch << 6;
    if (l0 >= len) return;
    const int nrows = min(64, len - l0);

    const int t = threadIdx.x;
    const int b = bk / 3;
    const int k = bk - b * 3;
    const float scale = w[k] / (float)len;

    const float4* xp = x4 + ((bk * LSEQ + l0) * (DM / 4)) + t;

    float ax0=0.f, ay0=0.f, az0=0.f, aw0=0.f;
    float ax1=0.f, ay1=0.f, az1=0.f, aw1=0.f;
    int r = 0;
    for (; r + 2 <= nrows; r += 2) {
        float4 v0 = xp[(r    ) * (DM / 4)];
        float4 v1 = xp[(r + 1) * (DM / 4)];
        ax0 += v0.x; ay0 += v0.y; az0 += v0.z; aw0 += v0.w;
        ax1 += v1.x; ay1 += v1.y; az1 += v1.z; aw1 += v1.w;
    }
    if (r < nrows) {
        float4 v0 = xp[r * (DM / 4)];
        ax0 += v0.x; ay0 += v0.y; az0 += v0.z; aw0 += v0.w;
    }
    ax0 = (ax0 + ax1) * scale;
    ay0 = (ay0 + ay1) * scale;
    az0 = (az0 + az1) * scale;
    aw0 = (aw0 + aw1) * scale;

    float* yp = y + b * DM + t * 4;
    atomicAdd(yp + 0, ax0);
    atomicAdd(yp + 1, ay0);
    atomicAdd(yp + 2, az0);
    atomicAdd(yp + 3, aw0);
}

// ---------------------------------------------------------------------------
// Kernel 3 (v2, LDS-size fixed): feature[b,h] = dot(y[b,:], W_proj[h,:]) + bp.
// Block = 4 h x 64 b. K-chunks of 128 floats staged in LDS, stride 129
// (129%32==1 -> compute reads hit bank (b+i)%32 = 2 lanes/bank, free):
//   LDS = 64*129*4 B = 33 KiB  (fits static limit; v1's 257 KiB did not!)
//   - global y loads coalesced (32 consecutive lanes read 512 B contiguous)
//   - W row wave-uniform (hh = t>>6 constant per wave) -> broadcast load;
//     W read exactly once total (4 MB)
//   - LDS transpose epilogue -> one float4 store per b-row
// ---------------------------------------------------------------------------
__global__ __launch_bounds__(256) void out_kernel(
    const float4* __restrict__ y4, const float4* __restrict__ W4,
    const float4* __restrict__ bp4, float4* __restrict__ out4)
{
    __shared__ float ylds[64 * 129];
    const int t  = threadIdx.x;
    const int b  = t & 63;
    const int hh = t >> 6;
    const int h  = (blockIdx.x << 2) + hh;

    float acc = 0.f;
    for (int c = 0; c < 8; ++c) {
        __syncthreads();
        #pragma unroll
        for (int j = 0; j < 8; ++j) {
            int flat = j * 256 + t;          // 0..2047
            int row  = flat >> 5;            // 0..63
            int col4 = flat & 31;            // 0..31 (float4 col in chunk)
            float4 v = y4[row * 256 + c * 32 + col4];
            float* p = &ylds[row * 129 + (col4 << 2)];
            p[0] = v.x; p[1] = v.y; p[2] = v.z; p[3] = v.w;
        }
        __syncthreads();
        const float* yr = &ylds[b * 129];
        #pragma unroll
        for (int j = 0; j < 32; ++j) {
            float4 wv = W4[h * 256 + c * 32 + j];
            int i = j << 2;
            acc += yr[i]     * wv.x + yr[i + 1] * wv.y
                 + yr[i + 2] * wv.z + yr[i + 3] * wv.w;
        }
    }

    __syncthreads();
    ylds[hh * 64 + b] = acc;
    __syncthreads();
    if (t < 64) {
        float4 bv = bp4[blockIdx.x];
        float4 v;
        v.x = ylds[0 * 64 + t] + bv.x;
        v.y = ylds[1 * 64 + t] + bv.y;
        v.z = ylds[2 * 64 + t] + bv.z;
        v.w = ylds[3 * 64 + t] + bv.w;
        out4[t * (HDIM / 4) + blockIdx.x] = v;
    }
}

extern "C" void kernel_launch(void* const* d_in, const int* in_sizes, int n_in,
                              void* d_out, int out_size, void* d_ws, size_t ws_size,
                              hipStream_t stream) {
    const float*         gf   = (const float*)d_in[0];         // (DM,)
    const float*         x    = (const float*)d_in[1];         // (B,3,L,DM)
    const unsigned char* mask = (const unsigned char*)d_in[2]; // (B,3,L)
    const float*         Wp   = (const float*)d_in[3];         // (H,DM)
    const float*         bp   = (const float*)d_in[4];         // (H,)
    const float*         Wc   = (const float*)d_in[5];         // (3,DM)
    const float*         bc   = (const float*)d_in[6];         // (3,)
    float* out = (float*)d_out;                                // (B,H)

    // ws layout (floats): [0..3]=w, [4..195]=cnts(int), [196]=flag,
    //                     [256..65791]=y
    float* wsf  = (float*)d_ws;
    float* w    = wsf;
    int*   cnts = (int*)(wsf + 4);
    int*   flag = (int*)(wsf + 196);
    float* y    = wsf + 256;   // byte offset 1024 -> float4-aligned

    detect_kernel<<<1, 256, 0, stream>>>((const unsigned*)mask, flag);
    prep_kernel<<<256, 256, 0, stream>>>(gf, mask, Wc, bc, flag, w, cnts, y);
    pool_kernel<<<NBK * NCH, 256, 0, stream>>>((const float4*)x, w, cnts, y);
    out_kernel<<<HDIM / 4, 256, 0, stream>>>((const float4*)y, (const float4*)Wp,
                                             (const float4*)bp, (float4*)out);
}